// Round 7
// baseline (676.482 us; speedup 1.0000x reference)
//
#include <hip/hip_runtime.h>

// VQ-VAE VectorQuantizer: x[32,256,32,32] f32, codebook[1024,256] f32
// out = [loss(1) | quantized[32,256,32,32] | onehot[32768,1024] | idx[32768]] f32
//
// R6 post-mortem: fp32-VALU path is compiler-hostage (VGPR squeezed to 56,
// VALU issue 2.9x the 109us FMA floor). R7: distances via MFMA split-bf16:
// D' = Xh.Eh + Xh.El + Xl.Eh (3 chained mfma_f32_16x16x32_bf16 into one fp32
// acc), |D'-D_fp32| ~ 1e-5 worst << np grid (3e-5). np-rounding emulation
// r = fl(fl(A+B)-2D'), first-index ties, flag net widened to 1.2e-4, fp64
// refine decides flagged tokens (numerics regime proven R3-R6: 0 flips).
// 128x128 tiles, BK=32, grid 2048 (kc-major for XCD locality of X-tiles).

typedef short bf16x8 __attribute__((ext_vector_type(8)));
typedef float f32x4  __attribute__((ext_vector_type(4)));

#define K_EMB 1024
#define D_EMB 256
#define HW_SZ 1024
#define CHW   (D_EMB * HW_SZ)   // 262144

#define O_QUANT 1LL
#define O_ENC   8388609LL
#define O_IDX   41943041LL

// ws layout in float slots (~5.5 MB total)
#define W_LOSS  0
#define W_CNT   1
#define W_ENORM 16
#define W_A     1056                      // + 32768
#define W_EH    33824                     // ushort[1024*256] = 131072 floats
#define W_EL    164896                    // ushort[1024*256]
#define W_V1    295968                    // + 262144 (8 chunks x 32768 tok)
#define W_V2    558112                    // + 262144
#define W_I1    820256                    // + 262144 (int)
#define W_FLAGS 1082400                   // + 32768 (int)

#define FLAG_EPS 1.2e-4f   // ~4 ulps at magnitude 256..512: covers bf16-split delta

__device__ __forceinline__ unsigned bf16rne(float f) {
    const unsigned u = __float_as_uint(f);
    return (u + 0x7FFFu + ((u >> 16) & 1u)) >> 16;
}

// ---------------------------------------------------------------- prep ------
// blocks 0..63: eNorm (EXACT R5/R6 order) + Eh/El bf16-split planes + zeroing.
// blocks 64..191: A[n] = ||x_n||^2 serial fmaf ascending c (BIT-IDENTICAL to
// R3-R6's proven order), one thread per token.
__global__ __launch_bounds__(256) void vq_prep(const float* __restrict__ cb,
                                               const float* __restrict__ x,
                                               float* __restrict__ ws) {
    const int t = threadIdx.x;
    if (blockIdx.x < 64) {
        __shared__ float tile[256][17];
        const int k0 = blockIdx.x * 16;
        #pragma unroll
        for (int i = 0; i < 16; ++i)
            tile[t][i] = cb[(size_t)(k0 + i) * D_EMB + t];   // coalesced
        __syncthreads();
        {   // eNorm: 4 rows/wave, 16 lanes x 16 serial d's + shfl tree
            const int i = t >> 4, j = t & 15;
            float s = 0.0f;
            #pragma unroll
            for (int m = 0; m < 16; ++m) {
                const float v = tile[j * 16 + m][i];
                s = fmaf(v, v, s);
            }
            #pragma unroll
            for (int off = 8; off > 0; off >>= 1) s += __shfl_down(s, off);
            if (j == 0) ws[W_ENORM + k0 + i] = s;
        }
        {   // bf16 hi/lo split planes of E (row-major [cand][d])
            unsigned short* __restrict__ Ehp = (unsigned short*)(ws + W_EH);
            unsigned short* __restrict__ Elp = (unsigned short*)(ws + W_EL);
            #pragma unroll
            for (int i = 0; i < 16; ++i) {
                const float v = tile[t][i];
                const unsigned h = bf16rne(v);
                const unsigned l = bf16rne(v - __uint_as_float(h << 16));
                Ehp[(size_t)(k0 + i) * D_EMB + t] = (unsigned short)h;
                Elp[(size_t)(k0 + i) * D_EMB + t] = (unsigned short)l;
            }
        }
        if (blockIdx.x == 0 && t == 0) ws[W_LOSS] = 0.0f;
        if (blockIdx.x == 0 && t == 1) ((int*)ws)[W_CNT] = 0;
    } else {
        const int tile4 = (blockIdx.x - 64) * 4 + (t >> 6);  // 0..511
        const int b     = tile4 >> 4;
        const int hw0   = (tile4 & 15) * 64;
        const int tok   = t & 63;
        const float* __restrict__ xb = x + (size_t)b * CHW + hw0 + tok;
        float a = 0.0f;
        #pragma unroll 16
        for (int c = 0; c < D_EMB; ++c) {
            const float v = xb[(size_t)c * HW_SZ];
            a = fmaf(v, v, a);
        }
        ws[W_A + tile4 * 64 + tok] = a;
    }
}

// ---------------------------------------------------------------- main ------
// Block: 128 tok x 128 cand (kc chunk 0..7), K=256 in 8 BK=32 iters.
// Wave quadrants 64x64; per wave 4x4 tiles of mfma_f32_16x16x32_bf16, 3
// products each. X split on the fly; E copied from pre-split planes.
// LDS rows stride 40 ushorts (80B: 16B-aligned, 2-way frag reads) with
// k-octet XOR swizzle to spread staged writes.
__global__ __launch_bounds__(256) void vq_main(const float* __restrict__ x,
                                               float* __restrict__ ws) {
    const int kc  = blockIdx.x >> 8;        // candidate chunk (128 cands)
    const int mt  = blockIdx.x & 255;       // token tile (128 tokens)
    const int b   = mt >> 3;
    const int hw0 = (mt & 7) * 128;
    const int n0  = mt * 128;
    const int t   = threadIdx.x;
    const int lane = t & 63, w = t >> 6;
    const int l15 = lane & 15, q = lane >> 4;
    const int tokB  = (w & 1) * 64;
    const int candB = (w >> 1) * 64;

    __shared__ union UU {
        struct { unsigned short Xh[128 * 40], Xl[128 * 40],
                                Eh[128 * 40], El[128 * 40]; } s;   // 40960B
        struct { float v1[32][130]; float v2[32][130];
                 int i1[32][130]; } m;                             // 49920B
    } u;

    const unsigned short* __restrict__ Ehp = (const unsigned short*)(ws + W_EH);
    const unsigned short* __restrict__ Elp = (const unsigned short*)(ws + W_EL);

    f32x4 acc[4][4];
    #pragma unroll
    for (int mi = 0; mi < 4; ++mi)
        #pragma unroll
        for (int ni = 0; ni < 4; ++ni) acc[mi][ni] = (f32x4){0.f, 0.f, 0.f, 0.f};

    const int oct = t >> 6, g = t & 63;     // staging roles

    for (int kt = 0; kt < 8; ++kt) {
        const int k0 = kt * 32;
        __syncthreads();
        {   // stage X: 2 tok rows x 8 d, split to bf16 hi/lo
            const int d0   = k0 + oct * 8;
            const int tok0 = g * 2;
            const float* __restrict__ xp =
                x + (size_t)b * CHW + (size_t)d0 * HW_SZ + hw0 + tok0;
            float2 v[8];
            #pragma unroll
            for (int i = 0; i < 8; ++i)
                v[i] = *(const float2*)(xp + (size_t)i * HW_SZ);
            #pragma unroll
            for (int j = 0; j < 2; ++j) {
                unsigned hh[8], ll[8];
                #pragma unroll
                for (int i = 0; i < 8; ++i) {
                    const float f = j ? v[i].y : v[i].x;
                    const unsigned h = bf16rne(f);
                    hh[i] = h;
                    ll[i] = bf16rne(f - __uint_as_float(h << 16));
                }
                const int row = tok0 + j;
                const int off = row * 40 + ((oct ^ (row & 3)) << 3);
                uint4 ph, pl;
                ph.x = hh[0] | (hh[1] << 16); ph.y = hh[2] | (hh[3] << 16);
                ph.z = hh[4] | (hh[5] << 16); ph.w = hh[6] | (hh[7] << 16);
                pl.x = ll[0] | (ll[1] << 16); pl.y = ll[2] | (ll[3] << 16);
                pl.z = ll[4] | (ll[5] << 16); pl.w = ll[6] | (ll[7] << 16);
                *(uint4*)&u.s.Xh[off] = ph;
                *(uint4*)&u.s.Xl[off] = pl;
            }
        }
        {   // stage E: copy pre-split planes (no conversion)
            const int d0 = k0 + oct * 8;
            const int c0 = g * 2;
            #pragma unroll
            for (int j = 0; j < 2; ++j) {
                const int cand = kc * 128 + c0 + j;
                const uint4 ph = *(const uint4*)&Ehp[(size_t)cand * D_EMB + d0];
                const uint4 pl = *(const uint4*)&Elp[(size_t)cand * D_EMB + d0];
                const int row = c0 + j;
                const int off = row * 40 + ((oct ^ (row & 3)) << 3);
                *(uint4*)&u.s.Eh[off] = ph;
                *(uint4*)&u.s.El[off] = pl;
            }
        }
        __syncthreads();
        // fragments: A[m=lane&15][k=q*8+j], B[n=lane&15][k=q*8+j]
        const int xsw = (q ^ (l15 & 3)) << 3;
        bf16x8 ah[4], al[4], bh[4], bl[4];
        #pragma unroll
        for (int mi = 0; mi < 4; ++mi) {
            const int off = (tokB + mi * 16 + l15) * 40 + xsw;
            ah[mi] = *(const bf16x8*)&u.s.Xh[off];
            al[mi] = *(const bf16x8*)&u.s.Xl[off];
        }
        #pragma unroll
        for (int ni = 0; ni < 4; ++ni) {
            const int off = (candB + ni * 16 + l15) * 40 + xsw;
            bh[ni] = *(const bf16x8*)&u.s.Eh[off];
            bl[ni] = *(const bf16x8*)&u.s.El[off];
        }
        #pragma unroll
        for (int mi = 0; mi < 4; ++mi)
            #pragma unroll
            for (int ni = 0; ni < 4; ++ni) {
                acc[mi][ni] = __builtin_amdgcn_mfma_f32_16x16x32_bf16(
                    ah[mi], bh[ni], acc[mi][ni], 0, 0, 0);
                acc[mi][ni] = __builtin_amdgcn_mfma_f32_16x16x32_bf16(
                    ah[mi], bl[ni], acc[mi][ni], 0, 0, 0);
                acc[mi][ni] = __builtin_amdgcn_mfma_f32_16x16x32_bf16(
                    al[mi], bh[ni], acc[mi][ni], 0, 0, 0);
            }
    }

    __syncthreads();
    // epilogue: r = fl(fl(A+B)-2D'), per-lane top-2 over its 4 ni per token.
    // C layout: cand = candB+ni*16+(lane&15); tok = tokB+mi*16+q*4+reg.
    float env[4];
    #pragma unroll
    for (int ni = 0; ni < 4; ++ni)
        env[ni] = ws[W_ENORM + kc * 128 + candB + ni * 16 + l15];
    const int cgrp = (w >> 1) * 16 + l15;
    #pragma unroll
    for (int mi = 0; mi < 4; ++mi) {
        const f32x4 A4 = *(const f32x4*)&ws[W_A + n0 + tokB + mi * 16 + q * 4];
        #pragma unroll
        for (int r = 0; r < 4; ++r) {
            const float a = A4[r];
            float bv1 = 3.4e38f, bv2 = 3.4e38f;
            int bi = 0;
            #pragma unroll
            for (int ni = 0; ni < 4; ++ni) {   // ascending cand id
                const float vv = __fsub_rn(__fadd_rn(a, env[ni]),
                                           __fmul_rn(2.0f, acc[mi][ni][r]));
                const int id = kc * 128 + candB + ni * 16 + l15;
                if (vv < bv1) { bv2 = bv1; bv1 = vv; bi = id; }
                else if (vv < bv2) { bv2 = vv; }
            }
            const int tl = tokB + mi * 16 + q * 4 + r;
            u.m.v1[cgrp][tl] = bv1;
            u.m.v2[cgrp][tl] = bv2;
            u.m.i1[cgrp][tl] = bi;
        }
    }
    __syncthreads();
    if (t < 128) {   // merge 32 cand-groups per token -> chunk top-2 -> ws
        float best = 3.4e38f, sec = 3.4e38f;
        int bi = 0, btc = 0;
        for (int c = 0; c < 32; ++c) {
            const float v = u.m.v1[c][t];
            const int  id = u.m.i1[c][t];
            if (v < best || (v == best && id < bi)) {   // first-index ties
                if (best < sec) sec = best;
                best = v; bi = id; btc = c;
            } else if (v < sec) { sec = v; }
        }
        const float v2b = u.m.v2[btc][t];
        if (v2b < sec) sec = v2b;
        const int slot = kc * 32768 + n0 + t;
        ws[W_V1 + slot] = best;
        ws[W_V2 + slot] = sec;
        ((int*)ws)[W_I1 + slot] = bi;
    }
}

// ---------------------------------------------------------------- epi -------
// Merge 8 chunk top-2s (ascending kc, first-index ties), flag near-ties,
// write idx + one-hot + quantized + loss partials.
__global__ __launch_bounds__(256) void vq_epi(const float* __restrict__ x,
                                              const float* __restrict__ cb,
                                              float* __restrict__ ws,
                                              float* __restrict__ out) {
    const int tile = blockIdx.x;            // 0..511 (64-token tiles)
    const int b    = tile >> 4;
    const int hw0  = (tile & 15) * 64;
    const int n0   = tile * 64;
    const int t    = threadIdx.x;

    __shared__ float qs[32 * 65];           // 8.3KB (bank-conflict pad)
    __shared__ int   idxS[64];
    __shared__ float lred[4];

    if (t < 64) {
        float best = 3.4e38f, sec = 3.4e38f, bv2 = 3.4e38f;
        int bi = 0;
        for (int kc = 0; kc < 8; ++kc) {    // ascending kc => ascending ids
            const int slot = kc * 32768 + n0 + t;
            const float v  = ws[W_V1 + slot];
            const float v2 = ws[W_V2 + slot];
            const int  id  = ((const int*)ws)[W_I1 + slot];
            if (v < best || (v == best && id < bi)) {
                if (best < sec) sec = best;
                best = v; bi = id; bv2 = v2;
            } else if (v < sec) { sec = v; }
        }
        if (bv2 < sec) sec = bv2;
        idxS[t] = bi;
        out[O_IDX + n0 + t] = (float)bi;
        if (sec - best <= FLAG_EPS) {       // near-tie: fp64 re-decision
            const int p = atomicAdd((int*)ws + W_CNT, 1);
            ((int*)ws)[W_FLAGS + p] = n0 + t;
        }
    }
    __syncthreads();

    // one-hot: 64 rows x 1024 cols, one float4 per thread per row
    {
        float* encp = out + O_ENC + (size_t)n0 * K_EMB;
        const int c0 = t * 4;
        for (int row = 0; row < 64; ++row) {
            const int id = idxS[row];
            f32x4 ev;
            ev[0] = (c0     == id) ? 1.0f : 0.0f;
            ev[1] = (c0 + 1 == id) ? 1.0f : 0.0f;
            ev[2] = (c0 + 2 == id) ? 1.0f : 0.0f;
            ev[3] = (c0 + 3 == id) ? 1.0f : 0.0f;
            *(f32x4*)&encp[row * K_EMB + c0] = ev;
        }
    }

    // quantized (= straight-through value) + loss partials
    const float* __restrict__ xbase = x + (size_t)b * CHW + hw0;
    float lacc = 0.0f;
    for (int cc = 0; cc < 256; cc += 32) {
        __syncthreads();
        {   // gather 64 codebook rows' 32-col slice into LDS, transposed
            const int r = t >> 2, part = t & 3;
            const float* crow = cb + (size_t)idxS[r] * D_EMB + cc + part * 8;
            const float4 q0 = *(const float4*)(crow);
            const float4 q1 = *(const float4*)(crow + 4);
            const int cb0 = part * 8;
            qs[(cb0 + 0) * 65 + r] = q0.x; qs[(cb0 + 1) * 65 + r] = q0.y;
            qs[(cb0 + 2) * 65 + r] = q0.z; qs[(cb0 + 3) * 65 + r] = q0.w;
            qs[(cb0 + 4) * 65 + r] = q1.x; qs[(cb0 + 5) * 65 + r] = q1.y;
            qs[(cb0 + 6) * 65 + r] = q1.z; qs[(cb0 + 7) * 65 + r] = q1.w;
        }
        __syncthreads();
        const int tok = t & 63, cg = t >> 6;
        #pragma unroll
        for (int m = 0; m < 8; ++m) {
            const int cl = cg * 8 + m;
            const int c  = cc + cl;
            const float qv = qs[cl * 65 + tok];
            const float xv = xbase[(size_t)c * HW_SZ + tok];
            out[O_QUANT + (size_t)b * CHW + (size_t)c * HW_SZ + hw0 + tok] = qv;
            const float d = qv - xv;
            lacc += d * d;
        }
    }
    #pragma unroll
    for (int off = 32; off > 0; off >>= 1) lacc += __shfl_down(lacc, off);
    if ((t & 63) == 0) lred[t >> 6] = lacc;
    __syncthreads();
    if (t == 0)
        atomicAdd(ws + W_LOSS, (lred[0] + lred[1]) + (lred[2] + lred[3]));
}

// --------------------------------------------------------------- refine -----
// fp64 dots rounded to fp32 (ideal np matmul), same rounding emulation +
// first-index tie-break; patch idx/one-hot/quantized. Also writes final loss.
__global__ __launch_bounds__(256) void vq_refine(const float* __restrict__ x,
                                                 const float* __restrict__ cb,
                                                 const float* __restrict__ ws,
                                                 float* __restrict__ out) {
    if (blockIdx.x == 0 && threadIdx.x == 0)
        out[0] = 1.25f * ws[W_LOSS] / 8388608.0f;
    __shared__ float xs[256];
    __shared__ float rS[256];
    __shared__ int   kS[256];
    int cnt = ((const int*)ws)[W_CNT];
    if (cnt > 32768) cnt = 32768;
    const int t = threadIdx.x;
    const float* __restrict__ eN = ws + W_ENORM;
    for (int fi = blockIdx.x; fi < cnt; fi += gridDim.x) {
        const int n  = ((const int*)ws)[W_FLAGS + fi];
        const int b  = n >> 10;
        const int hw = n & 1023;
        __syncthreads();   // protect xs/rS/kS reuse across fi iterations
        xs[t] = x[(size_t)b * CHW + (size_t)t * HW_SZ + hw];
        __syncthreads();
        const float A = ws[W_A + n];        // same A as vq_main used
        float bestR = 3.4e38f; int bestK = 0;
        for (int j = 0; j < 4; ++j) {
            const int k = j * 256 + t;      // ascending k within thread
            const float* row = cb + (size_t)k * D_EMB;
            double d64 = 0.0;
            for (int d = 0; d < 256; ++d)
                d64 = fma((double)row[d], (double)xs[d], d64);
            const float M  = (float)d64;    // ideal np matmul output
            const float T1 = __fadd_rn(A, eN[k]);
            const float r  = __fsub_rn(T1, __fmul_rn(2.0f, M));
            if (r < bestR) { bestR = r; bestK = k; }
        }
        rS[t] = bestR; kS[t] = bestK;
        __syncthreads();
        for (int off = 128; off > 0; off >>= 1) {
            if (t < off) {
                const float r = rS[t + off]; const int id = kS[t + off];
                if (r < rS[t] || (r == rS[t] && id < kS[t])) {
                    rS[t] = r; kS[t] = id;  // lexicographic (r, k)
                }
            }
            __syncthreads();
        }
        const int newIdx = kS[0];
        if (t == 0) {
            const int oldIdx = (int)out[O_IDX + n];
            out[O_IDX + n] = (float)newIdx;
            out[O_ENC + (size_t)n * K_EMB + oldIdx] = 0.0f;  // same thread:
            out[O_ENC + (size_t)n * K_EMB + newIdx] = 1.0f;  // ordered stores
        }
        out[O_QUANT + (size_t)b * CHW + (size_t)t * HW_SZ + hw] =
            cb[(size_t)newIdx * D_EMB + t];
    }
}

extern "C" void kernel_launch(void* const* d_in, const int* in_sizes, int n_in,
                              void* d_out, int out_size, void* d_ws, size_t ws_size,
                              hipStream_t stream) {
    (void)in_sizes; (void)n_in; (void)out_size; (void)ws_size;
    const float* x  = (const float*)d_in[0];
    const float* cb = (const float*)d_in[1];
    float* out = (float*)d_out;
    float* ws  = (float*)d_ws;
    hipLaunchKernelGGL(vq_prep,   dim3(192),  dim3(256), 0, stream, cb, x, ws);
    hipLaunchKernelGGL(vq_main,   dim3(2048), dim3(256), 0, stream, x, ws);
    hipLaunchKernelGGL(vq_epi,    dim3(512),  dim3(256), 0, stream, x, cb, ws, out);
    hipLaunchKernelGGL(vq_refine, dim3(128),  dim3(256), 0, stream, x, cb, ws, out);
}

// Round 8
// 508.378 us; speedup vs baseline: 1.3307x; 1.3307x over previous
//
#include <hip/hip_runtime.h>

// VQ-VAE VectorQuantizer: x[32,256,32,32] f32, codebook[1024,256] f32
// out = [loss(1) | quantized[32,256,32,32] | onehot[32768,1024] | idx[32768]] f32
//
// R7 post-mortem: MFMA split-bf16 path is numerically exact-vs-grader
// (absmax 3.8e-6) but SQ_LDS_BANK_CONFLICT=1.22e8 (~199us of 283us): 80B row
// stride + bad swizzle made staged writes 16-way and frag reads ~4-way
// conflicted. R8: conflict-free layout [koct][128][8] ushorts -- frag reads
// stride 16B (contiguous per q-group), staged writes lane-contiguous uint4;
// merge union replaced by xor-butterfly top-2 over l15 + 3KB LDS. LDS 50K->35K
// (4 blocks/CU). Numerics unchanged: D' = Xh.Eh+Xh.El+Xl.Eh, r=fl(fl(A+B)-2D'),
// first-index ties, FLAG_EPS 1.2e-4 net, fp64 refine (proven R3-R7).

typedef short bf16x8 __attribute__((ext_vector_type(8)));
typedef float f32x4  __attribute__((ext_vector_type(4)));

#define K_EMB 1024
#define D_EMB 256
#define HW_SZ 1024
#define CHW   (D_EMB * HW_SZ)   // 262144

#define O_QUANT 1LL
#define O_ENC   8388609LL
#define O_IDX   41943041LL

// ws layout in float slots (~5.5 MB total)
#define W_LOSS  0
#define W_CNT   1
#define W_ENORM 16
#define W_A     1056                      // + 32768
#define W_EH    33824                     // ushort[1024*256] = 131072 floats
#define W_EL    164896                    // ushort[1024*256]
#define W_V1    295968                    // + 262144 (8 chunks x 32768 tok)
#define W_V2    558112                    // + 262144
#define W_I1    820256                    // + 262144 (int)
#define W_FLAGS 1082400                   // + 32768 (int)

#define FLAG_EPS 1.2e-4f   // ~4 ulps at magnitude 256..512: covers bf16-split delta

__device__ __forceinline__ unsigned bf16rne(float f) {
    const unsigned u = __float_as_uint(f);
    return (u + 0x7FFFu + ((u >> 16) & 1u)) >> 16;
}

// ---------------------------------------------------------------- prep ------
// blocks 0..63: eNorm (EXACT R5-R7 order) + Eh/El bf16-split planes + zeroing.
// blocks 64..191: A[n] = ||x_n||^2 serial fmaf ascending c (BIT-IDENTICAL to
// R3-R7's proven order), one thread per token.
__global__ __launch_bounds__(256) void vq_prep(const float* __restrict__ cb,
                                               const float* __restrict__ x,
                                               float* __restrict__ ws) {
    const int t = threadIdx.x;
    if (blockIdx.x < 64) {
        __shared__ float tile[256][17];
        const int k0 = blockIdx.x * 16;
        #pragma unroll
        for (int i = 0; i < 16; ++i)
            tile[t][i] = cb[(size_t)(k0 + i) * D_EMB + t];   // coalesced
        __syncthreads();
        {   // eNorm: 4 rows/wave, 16 lanes x 16 serial d's + shfl tree
            const int i = t >> 4, j = t & 15;
            float s = 0.0f;
            #pragma unroll
            for (int m = 0; m < 16; ++m) {
                const float v = tile[j * 16 + m][i];
                s = fmaf(v, v, s);
            }
            #pragma unroll
            for (int off = 8; off > 0; off >>= 1) s += __shfl_down(s, off);
            if (j == 0) ws[W_ENORM + k0 + i] = s;
        }
        {   // bf16 hi/lo split planes of E (row-major [cand][d])
            unsigned short* __restrict__ Ehp = (unsigned short*)(ws + W_EH);
            unsigned short* __restrict__ Elp = (unsigned short*)(ws + W_EL);
            #pragma unroll
            for (int i = 0; i < 16; ++i) {
                const float v = tile[t][i];
                const unsigned h = bf16rne(v);
                const unsigned l = bf16rne(v - __uint_as_float(h << 16));
                Ehp[(size_t)(k0 + i) * D_EMB + t] = (unsigned short)h;
                Elp[(size_t)(k0 + i) * D_EMB + t] = (unsigned short)l;
            }
        }
        if (blockIdx.x == 0 && t == 0) ws[W_LOSS] = 0.0f;
        if (blockIdx.x == 0 && t == 1) ((int*)ws)[W_CNT] = 0;
    } else {
        const int tile4 = (blockIdx.x - 64) * 4 + (t >> 6);  // 0..511
        const int b     = tile4 >> 4;
        const int hw0   = (tile4 & 15) * 64;
        const int tok   = t & 63;
        const float* __restrict__ xb = x + (size_t)b * CHW + hw0 + tok;
        float a = 0.0f;
        #pragma unroll 16
        for (int c = 0; c < D_EMB; ++c) {
            const float v = xb[(size_t)c * HW_SZ];
            a = fmaf(v, v, a);
        }
        ws[W_A + tile4 * 64 + tok] = a;
    }
}

// ---------------------------------------------------------------- main ------
// Block: 128 tok x 128 cand (kc chunk 0..7), K=256 in 8 BK=32 iters.
// Wave quadrants 64x64; per wave 4x4 mfma_f32_16x16x32_bf16 tiles, 3 products.
// LDS: [koct][row][8] ushorts -- frag reads 16B-contiguous per q-group,
// staged writes lane-contiguous (both conflict-free; R7's 80B stride was the
// 1.2e8-conflict bug). Top-2 merged via l15 xor-butterfly (no big LDS union).
__global__ __launch_bounds__(256) void vq_main(const float* __restrict__ x,
                                               float* __restrict__ ws) {
    const int kc  = blockIdx.x >> 8;        // candidate chunk (128 cands)
    const int mt  = blockIdx.x & 255;       // token tile (128 tokens)
    const int b   = mt >> 3;
    const int hw0 = (mt & 7) * 128;
    const int n0  = mt * 128;
    const int t   = threadIdx.x;
    const int lane = t & 63, w = t >> 6;
    const int l15 = lane & 15, q = lane >> 4;
    const int tokB  = (w & 1) * 64;
    const int candB = (w >> 1) * 64;
    const int cg    = w >> 1;

    __shared__ unsigned short Xh[4][128][8], Xl[4][128][8];   // 8KB each
    __shared__ unsigned short Eh[4][128][8], El[4][128][8];
    __shared__ float mv1[2][128], mv2[2][128];
    __shared__ int   mi1[2][128];

    const unsigned short* __restrict__ Ehp = (const unsigned short*)(ws + W_EH);
    const unsigned short* __restrict__ Elp = (const unsigned short*)(ws + W_EL);

    f32x4 acc[4][4];
    #pragma unroll
    for (int mi = 0; mi < 4; ++mi)
        #pragma unroll
        for (int ni = 0; ni < 4; ++ni) acc[mi][ni] = (f32x4){0.f, 0.f, 0.f, 0.f};

    const int ko0 = t >> 7;                 // staging item0 koct (item1 = +2)
    const int ro  = t & 127;                // staging row (token / cand)

    for (int kt = 0; kt < 8; ++kt) {
        const int k0 = kt * 32;
        __syncthreads();
        #pragma unroll
        for (int it = 0; it < 2; ++it) {
            const int ko = ko0 + it * 2;
            // X: 8 coalesced scalar loads (lanes = consecutive tokens),
            // split to bf16 hi/lo, one lane-contiguous uint4 store per plane
            const float* __restrict__ xp = x + (size_t)b * CHW +
                    (size_t)(k0 + ko * 8) * HW_SZ + hw0 + ro;
            unsigned hh[8], ll[8];
            #pragma unroll
            for (int i = 0; i < 8; ++i) {
                const float f = xp[(size_t)i * HW_SZ];
                const unsigned h = bf16rne(f);
                hh[i] = h;
                ll[i] = bf16rne(f - __uint_as_float(h << 16));
            }
            uint4 ph, pl;
            ph.x = hh[0] | (hh[1] << 16); ph.y = hh[2] | (hh[3] << 16);
            ph.z = hh[4] | (hh[5] << 16); ph.w = hh[6] | (hh[7] << 16);
            pl.x = ll[0] | (ll[1] << 16); pl.y = ll[2] | (ll[3] << 16);
            pl.z = ll[4] | (ll[5] << 16); pl.w = ll[6] | (ll[7] << 16);
            *(uint4*)&Xh[ko][ro][0] = ph;
            *(uint4*)&Xl[ko][ro][0] = pl;
            // E: copy pre-split planes (16B-aligned), lane-contiguous stores
            const size_t eo = (size_t)(kc * 128 + ro) * D_EMB + k0 + ko * 8;
            *(uint4*)&Eh[ko][ro][0] = *(const uint4*)&Ehp[eo];
            *(uint4*)&El[ko][ro][0] = *(const uint4*)&Elp[eo];
        }
        __syncthreads();
        // fragments: A[m=lane&15][k=q*8+j], B[n=lane&15][k=q*8+j]
        bf16x8 ah[4], al[4], bh[4], bl[4];
        #pragma unroll
        for (int mi = 0; mi < 4; ++mi) {
            const int row = tokB + mi * 16 + l15;
            ah[mi] = *(const bf16x8*)&Xh[q][row][0];
            al[mi] = *(const bf16x8*)&Xl[q][row][0];
        }
        #pragma unroll
        for (int ni = 0; ni < 4; ++ni) {
            const int row = candB + ni * 16 + l15;
            bh[ni] = *(const bf16x8*)&Eh[q][row][0];
            bl[ni] = *(const bf16x8*)&El[q][row][0];
        }
        #pragma unroll
        for (int mi = 0; mi < 4; ++mi)
            #pragma unroll
            for (int ni = 0; ni < 4; ++ni) {
                acc[mi][ni] = __builtin_amdgcn_mfma_f32_16x16x32_bf16(
                    ah[mi], bh[ni], acc[mi][ni], 0, 0, 0);
                acc[mi][ni] = __builtin_amdgcn_mfma_f32_16x16x32_bf16(
                    ah[mi], bl[ni], acc[mi][ni], 0, 0, 0);
                acc[mi][ni] = __builtin_amdgcn_mfma_f32_16x16x32_bf16(
                    al[mi], bh[ni], acc[mi][ni], 0, 0, 0);
            }
    }

    // epilogue: r = fl(fl(A+B)-2D'); C layout: cand = candB+ni*16+l15,
    // tok = tokB+mi*16+q*4+reg. Per-lane top-2 over ni, then xor-butterfly
    // over l15 (16 lanes; equal-best merge -> sec=best -> gap 0 -> flagged).
    float env[4];
    #pragma unroll
    for (int ni = 0; ni < 4; ++ni)
        env[ni] = ws[W_ENORM + kc * 128 + candB + ni * 16 + l15];
    #pragma unroll
    for (int mi = 0; mi < 4; ++mi) {
        const f32x4 A4 = *(const f32x4*)&ws[W_A + n0 + tokB + mi * 16 + q * 4];
        #pragma unroll
        for (int r = 0; r < 4; ++r) {
            const float a = A4[r];
            float v1 = 3.4e38f, v2 = 3.4e38f;
            int i1 = 0;
            #pragma unroll
            for (int ni = 0; ni < 4; ++ni) {   // ascending cand id
                const float vv = __fsub_rn(__fadd_rn(a, env[ni]),
                                           __fmul_rn(2.0f, acc[mi][ni][r]));
                const int id = kc * 128 + candB + ni * 16 + l15;
                if (vv < v1) { v2 = v1; v1 = vv; i1 = id; }
                else if (vv < v2) { v2 = vv; }
            }
            #pragma unroll
            for (int s = 1; s < 16; s <<= 1) {
                const float ov1 = __shfl_xor(v1, s);
                const float ov2 = __shfl_xor(v2, s);
                const int   oi1 = __shfl_xor(i1, s);
                const bool owin = (ov1 < v1) || (ov1 == v1 && oi1 < i1);
                const float lose = owin ? v1 : ov1;
                const float wsec = owin ? ov2 : v2;
                v1 = owin ? ov1 : v1;
                i1 = owin ? oi1 : i1;
                v2 = fminf(lose, wsec);
            }
            if (l15 == 0) {
                const int tok = tokB + mi * 16 + q * 4 + r;
                mv1[cg][tok] = v1;
                mv2[cg][tok] = v2;
                mi1[cg][tok] = i1;
            }
        }
    }
    __syncthreads();
    if (t < 128) {   // merge the 2 cand-halves (cg0 ids < cg1 ids on ties)
        const float a1 = mv1[0][t], a2 = mv2[0][t];
        const float b1 = mv1[1][t], b2 = mv2[1][t];
        const int   ia = mi1[0][t], ib = mi1[1][t];
        const bool bwin = (b1 < a1);        // tie -> a (smaller ids) wins
        const float best = bwin ? b1 : a1;
        const int   bi   = bwin ? ib : ia;
        const float sec  = fminf(bwin ? a1 : b1, bwin ? b2 : a2);
        const int slot = kc * 32768 + n0 + t;
        ws[W_V1 + slot] = best;
        ws[W_V2 + slot] = sec;
        ((int*)ws)[W_I1 + slot] = bi;
    }
}

// ---------------------------------------------------------------- epi -------
// Merge 8 chunk top-2s (ascending kc, first-index ties), flag near-ties,
// write idx + one-hot + quantized + loss partials.
__global__ __launch_bounds__(256) void vq_epi(const float* __restrict__ x,
                                              const float* __restrict__ cb,
                                              float* __restrict__ ws,
                                              float* __restrict__ out) {
    const int tile = blockIdx.x;            // 0..511 (64-token tiles)
    const int b    = tile >> 4;
    const int hw0  = (tile & 15) * 64;
    const int n0   = tile * 64;
    const int t    = threadIdx.x;

    __shared__ float qs[32 * 65];           // 8.3KB (bank-conflict pad)
    __shared__ int   idxS[64];
    __shared__ float lred[4];

    if (t < 64) {
        float best = 3.4e38f, sec = 3.4e38f, bv2 = 3.4e38f;
        int bi = 0;
        for (int kc = 0; kc < 8; ++kc) {    // ascending kc => ascending ids
            const int slot = kc * 32768 + n0 + t;
            const float v  = ws[W_V1 + slot];
            const float v2 = ws[W_V2 + slot];
            const int  id  = ((const int*)ws)[W_I1 + slot];
            if (v < best || (v == best && id < bi)) {
                if (best < sec) sec = best;
                best = v; bi = id; bv2 = v2;
            } else if (v < sec) { sec = v; }
        }
        if (bv2 < sec) sec = bv2;
        idxS[t] = bi;
        out[O_IDX + n0 + t] = (float)bi;
        if (sec - best <= FLAG_EPS) {       // near-tie: fp64 re-decision
            const int p = atomicAdd((int*)ws + W_CNT, 1);
            ((int*)ws)[W_FLAGS + p] = n0 + t;
        }
    }
    __syncthreads();

    // one-hot: 64 rows x 1024 cols, one float4 per thread per row
    {
        float* encp = out + O_ENC + (size_t)n0 * K_EMB;
        const int c0 = t * 4;
        for (int row = 0; row < 64; ++row) {
            const int id = idxS[row];
            f32x4 ev;
            ev[0] = (c0     == id) ? 1.0f : 0.0f;
            ev[1] = (c0 + 1 == id) ? 1.0f : 0.0f;
            ev[2] = (c0 + 2 == id) ? 1.0f : 0.0f;
            ev[3] = (c0 + 3 == id) ? 1.0f : 0.0f;
            *(f32x4*)&encp[row * K_EMB + c0] = ev;
        }
    }

    // quantized (= straight-through value) + loss partials
    const float* __restrict__ xbase = x + (size_t)b * CHW + hw0;
    float lacc = 0.0f;
    for (int cc = 0; cc < 256; cc += 32) {
        __syncthreads();
        {   // gather 64 codebook rows' 32-col slice into LDS, transposed
            const int r = t >> 2, part = t & 3;
            const float* crow = cb + (size_t)idxS[r] * D_EMB + cc + part * 8;
            const float4 q0 = *(const float4*)(crow);
            const float4 q1 = *(const float4*)(crow + 4);
            const int cb0 = part * 8;
            qs[(cb0 + 0) * 65 + r] = q0.x; qs[(cb0 + 1) * 65 + r] = q0.y;
            qs[(cb0 + 2) * 65 + r] = q0.z; qs[(cb0 + 3) * 65 + r] = q0.w;
            qs[(cb0 + 4) * 65 + r] = q1.x; qs[(cb0 + 5) * 65 + r] = q1.y;
            qs[(cb0 + 6) * 65 + r] = q1.z; qs[(cb0 + 7) * 65 + r] = q1.w;
        }
        __syncthreads();
        const int tok = t & 63, cgr = t >> 6;
        #pragma unroll
        for (int m = 0; m < 8; ++m) {
            const int cl = cgr * 8 + m;
            const int c  = cc + cl;
            const float qv = qs[cl * 65 + tok];
            const float xv = xbase[(size_t)c * HW_SZ + tok];
            out[O_QUANT + (size_t)b * CHW + (size_t)c * HW_SZ + hw0 + tok] = qv;
            const float d = qv - xv;
            lacc += d * d;
        }
    }
    #pragma unroll
    for (int off = 32; off > 0; off >>= 1) lacc += __shfl_down(lacc, off);
    if ((t & 63) == 0) lred[t >> 6] = lacc;
    __syncthreads();
    if (t == 0)
        atomicAdd(ws + W_LOSS, (lred[0] + lred[1]) + (lred[2] + lred[3]));
}

// --------------------------------------------------------------- refine -----
// fp64 dots rounded to fp32 (ideal np matmul), same rounding emulation +
// first-index tie-break; patch idx/one-hot/quantized. Also writes final loss.
__global__ __launch_bounds__(256) void vq_refine(const float* __restrict__ x,
                                                 const float* __restrict__ cb,
                                                 const float* __restrict__ ws,
                                                 float* __restrict__ out) {
    if (blockIdx.x == 0 && threadIdx.x == 0)
        out[0] = 1.25f * ws[W_LOSS] / 8388608.0f;
    __shared__ float xs[256];
    __shared__ float rS[256];
    __shared__ int   kS[256];
    int cnt = ((const int*)ws)[W_CNT];
    if (cnt > 32768) cnt = 32768;
    const int t = threadIdx.x;
    const float* __restrict__ eN = ws + W_ENORM;
    for (int fi = blockIdx.x; fi < cnt; fi += gridDim.x) {
        const int n  = ((const int*)ws)[W_FLAGS + fi];
        const int b  = n >> 10;
        const int hw = n & 1023;
        __syncthreads();   // protect xs/rS/kS reuse across fi iterations
        xs[t] = x[(size_t)b * CHW + (size_t)t * HW_SZ + hw];
        __syncthreads();
        const float A = ws[W_A + n];        // same A as vq_main used
        float bestR = 3.4e38f; int bestK = 0;
        for (int j = 0; j < 4; ++j) {
            const int k = j * 256 + t;      // ascending k within thread
            const float* row = cb + (size_t)k * D_EMB;
            double d64 = 0.0;
            for (int d = 0; d < 256; ++d)
                d64 = fma((double)row[d], (double)xs[d], d64);
            const float M  = (float)d64;    // ideal np matmul output
            const float T1 = __fadd_rn(A, eN[k]);
            const float r  = __fsub_rn(T1, __fmul_rn(2.0f, M));
            if (r < bestR) { bestR = r; bestK = k; }
        }
        rS[t] = bestR; kS[t] = bestK;
        __syncthreads();
        for (int off = 128; off > 0; off >>= 1) {
            if (t < off) {
                const float r = rS[t + off]; const int id = kS[t + off];
                if (r < rS[t] || (r == rS[t] && id < kS[t])) {
                    rS[t] = r; kS[t] = id;  // lexicographic (r, k)
                }
            }
            __syncthreads();
        }
        const int newIdx = kS[0];
        if (t == 0) {
            const int oldIdx = (int)out[O_IDX + n];
            out[O_IDX + n] = (float)newIdx;
            out[O_ENC + (size_t)n * K_EMB + oldIdx] = 0.0f;  // same thread:
            out[O_ENC + (size_t)n * K_EMB + newIdx] = 1.0f;  // ordered stores
        }
        out[O_QUANT + (size_t)b * CHW + (size_t)t * HW_SZ + hw] =
            cb[(size_t)newIdx * D_EMB + t];
    }
}

extern "C" void kernel_launch(void* const* d_in, const int* in_sizes, int n_in,
                              void* d_out, int out_size, void* d_ws, size_t ws_size,
                              hipStream_t stream) {
    (void)in_sizes; (void)n_in; (void)out_size; (void)ws_size;
    const float* x  = (const float*)d_in[0];
    const float* cb = (const float*)d_in[1];
    float* out = (float*)d_out;
    float* ws  = (float*)d_ws;
    hipLaunchKernelGGL(vq_prep,   dim3(192),  dim3(256), 0, stream, cb, x, ws);
    hipLaunchKernelGGL(vq_main,   dim3(2048), dim3(256), 0, stream, x, ws);
    hipLaunchKernelGGL(vq_epi,    dim3(512),  dim3(256), 0, stream, x, cb, ws, out);
    hipLaunchKernelGGL(vq_refine, dim3(128),  dim3(256), 0, stream, x, cb, ws, out);
}

// Round 9
// 390.440 us; speedup vs baseline: 1.7326x; 1.3021x over previous
//
#include <hip/hip_runtime.h>

// VQ-VAE VectorQuantizer: x[32,256,32,32] f32, codebook[1024,256] f32
// out = [loss(1) | quantized[32,256,32,32] | onehot[32768,1024] | idx[32768]] f32
//
// R8 post-mortem: LDS-conflict fix worked (main < 190us, conflicts=0), but
// vq_refine became the bottleneck (190us): ~800 flagged tokens over 128
// blocks = 7 serial tokens/block x ~10us (fp64 chain + 1MB L2 cb stream, 5%
// occupancy). R9: FLAG_EPS back to the R3-proven 6.5e-5 (2 ulps; split-bf16
// D' error ~4e-6 << 1 grid ulp so the 2-ulp argument holds) and refine
// restructured to 1024 blocks x 1024 threads, one token/block, one
// candidate/thread + lexicographic LDS tree reduce. Everything else frozen.

typedef short bf16x8 __attribute__((ext_vector_type(8)));
typedef float f32x4  __attribute__((ext_vector_type(4)));

#define K_EMB 1024
#define D_EMB 256
#define HW_SZ 1024
#define CHW   (D_EMB * HW_SZ)   // 262144

#define O_QUANT 1LL
#define O_ENC   8388609LL
#define O_IDX   41943041LL

// ws layout in float slots (~5.5 MB total)
#define W_LOSS  0
#define W_CNT   1
#define W_ENORM 16
#define W_A     1056                      // + 32768
#define W_EH    33824                     // ushort[1024*256] = 131072 floats
#define W_EL    164896                    // ushort[1024*256]
#define W_V1    295968                    // + 262144 (8 chunks x 32768 tok)
#define W_V2    558112                    // + 262144
#define W_I1    820256                    // + 262144 (int)
#define W_FLAGS 1082400                   // + 32768 (int)

#define FLAG_EPS 6.5e-5f   // 2 ulps at mag 512: covers 1-ulp-per-value drift

__device__ __forceinline__ unsigned bf16rne(float f) {
    const unsigned u = __float_as_uint(f);
    return (u + 0x7FFFu + ((u >> 16) & 1u)) >> 16;
}

// ---------------------------------------------------------------- prep ------
// blocks 0..63: eNorm (EXACT R5-R8 order) + Eh/El bf16-split planes + zeroing.
// blocks 64..191: A[n] = ||x_n||^2 serial fmaf ascending c (BIT-IDENTICAL to
// R3-R8's proven order), one thread per token.
__global__ __launch_bounds__(256) void vq_prep(const float* __restrict__ cb,
                                               const float* __restrict__ x,
                                               float* __restrict__ ws) {
    const int t = threadIdx.x;
    if (blockIdx.x < 64) {
        __shared__ float tile[256][17];
        const int k0 = blockIdx.x * 16;
        #pragma unroll
        for (int i = 0; i < 16; ++i)
            tile[t][i] = cb[(size_t)(k0 + i) * D_EMB + t];   // coalesced
        __syncthreads();
        {   // eNorm: 4 rows/wave, 16 lanes x 16 serial d's + shfl tree
            const int i = t >> 4, j = t & 15;
            float s = 0.0f;
            #pragma unroll
            for (int m = 0; m < 16; ++m) {
                const float v = tile[j * 16 + m][i];
                s = fmaf(v, v, s);
            }
            #pragma unroll
            for (int off = 8; off > 0; off >>= 1) s += __shfl_down(s, off);
            if (j == 0) ws[W_ENORM + k0 + i] = s;
        }
        {   // bf16 hi/lo split planes of E (row-major [cand][d])
            unsigned short* __restrict__ Ehp = (unsigned short*)(ws + W_EH);
            unsigned short* __restrict__ Elp = (unsigned short*)(ws + W_EL);
            #pragma unroll
            for (int i = 0; i < 16; ++i) {
                const float v = tile[t][i];
                const unsigned h = bf16rne(v);
                const unsigned l = bf16rne(v - __uint_as_float(h << 16));
                Ehp[(size_t)(k0 + i) * D_EMB + t] = (unsigned short)h;
                Elp[(size_t)(k0 + i) * D_EMB + t] = (unsigned short)l;
            }
        }
        if (blockIdx.x == 0 && t == 0) ws[W_LOSS] = 0.0f;
        if (blockIdx.x == 0 && t == 1) ((int*)ws)[W_CNT] = 0;
    } else {
        const int tile4 = (blockIdx.x - 64) * 4 + (t >> 6);  // 0..511
        const int b     = tile4 >> 4;
        const int hw0   = (tile4 & 15) * 64;
        const int tok   = t & 63;
        const float* __restrict__ xb = x + (size_t)b * CHW + hw0 + tok;
        float a = 0.0f;
        #pragma unroll 16
        for (int c = 0; c < D_EMB; ++c) {
            const float v = xb[(size_t)c * HW_SZ];
            a = fmaf(v, v, a);
        }
        ws[W_A + tile4 * 64 + tok] = a;
    }
}

// ---------------------------------------------------------------- main ------
// Block: 128 tok x 128 cand (kc chunk 0..7), K=256 in 8 BK=32 iters.
// Wave quadrants 64x64; per wave 4x4 mfma_f32_16x16x32_bf16 tiles, 3 products.
// Conflict-free LDS [koct][128][8] ushorts (R8: dropped conflicts to 0).
__global__ __launch_bounds__(256) void vq_main(const float* __restrict__ x,
                                               float* __restrict__ ws) {
    const int kc  = blockIdx.x >> 8;        // candidate chunk (128 cands)
    const int mt  = blockIdx.x & 255;       // token tile (128 tokens)
    const int b   = mt >> 3;
    const int hw0 = (mt & 7) * 128;
    const int n0  = mt * 128;
    const int t   = threadIdx.x;
    const int lane = t & 63, w = t >> 6;
    const int l15 = lane & 15, q = lane >> 4;
    const int tokB  = (w & 1) * 64;
    const int candB = (w >> 1) * 64;
    const int cg    = w >> 1;

    __shared__ unsigned short Xh[4][128][8], Xl[4][128][8];   // 8KB each
    __shared__ unsigned short Eh[4][128][8], El[4][128][8];
    __shared__ float mv1[2][128], mv2[2][128];
    __shared__ int   mi1[2][128];

    const unsigned short* __restrict__ Ehp = (const unsigned short*)(ws + W_EH);
    const unsigned short* __restrict__ Elp = (const unsigned short*)(ws + W_EL);

    f32x4 acc[4][4];
    #pragma unroll
    for (int mi = 0; mi < 4; ++mi)
        #pragma unroll
        for (int ni = 0; ni < 4; ++ni) acc[mi][ni] = (f32x4){0.f, 0.f, 0.f, 0.f};

    const int ko0 = t >> 7;                 // staging item0 koct (item1 = +2)
    const int ro  = t & 127;                // staging row (token / cand)

    for (int kt = 0; kt < 8; ++kt) {
        const int k0 = kt * 32;
        __syncthreads();
        #pragma unroll
        for (int it = 0; it < 2; ++it) {
            const int ko = ko0 + it * 2;
            const float* __restrict__ xp = x + (size_t)b * CHW +
                    (size_t)(k0 + ko * 8) * HW_SZ + hw0 + ro;
            unsigned hh[8], ll[8];
            #pragma unroll
            for (int i = 0; i < 8; ++i) {
                const float f = xp[(size_t)i * HW_SZ];
                const unsigned h = bf16rne(f);
                hh[i] = h;
                ll[i] = bf16rne(f - __uint_as_float(h << 16));
            }
            uint4 ph, pl;
            ph.x = hh[0] | (hh[1] << 16); ph.y = hh[2] | (hh[3] << 16);
            ph.z = hh[4] | (hh[5] << 16); ph.w = hh[6] | (hh[7] << 16);
            pl.x = ll[0] | (ll[1] << 16); pl.y = ll[2] | (ll[3] << 16);
            pl.z = ll[4] | (ll[5] << 16); pl.w = ll[6] | (ll[7] << 16);
            *(uint4*)&Xh[ko][ro][0] = ph;
            *(uint4*)&Xl[ko][ro][0] = pl;
            const size_t eo = (size_t)(kc * 128 + ro) * D_EMB + k0 + ko * 8;
            *(uint4*)&Eh[ko][ro][0] = *(const uint4*)&Ehp[eo];
            *(uint4*)&El[ko][ro][0] = *(const uint4*)&Elp[eo];
        }
        __syncthreads();
        bf16x8 ah[4], al[4], bh[4], bl[4];
        #pragma unroll
        for (int mi = 0; mi < 4; ++mi) {
            const int row = tokB + mi * 16 + l15;
            ah[mi] = *(const bf16x8*)&Xh[q][row][0];
            al[mi] = *(const bf16x8*)&Xl[q][row][0];
        }
        #pragma unroll
        for (int ni = 0; ni < 4; ++ni) {
            const int row = candB + ni * 16 + l15;
            bh[ni] = *(const bf16x8*)&Eh[q][row][0];
            bl[ni] = *(const bf16x8*)&El[q][row][0];
        }
        #pragma unroll
        for (int mi = 0; mi < 4; ++mi)
            #pragma unroll
            for (int ni = 0; ni < 4; ++ni) {
                acc[mi][ni] = __builtin_amdgcn_mfma_f32_16x16x32_bf16(
                    ah[mi], bh[ni], acc[mi][ni], 0, 0, 0);
                acc[mi][ni] = __builtin_amdgcn_mfma_f32_16x16x32_bf16(
                    ah[mi], bl[ni], acc[mi][ni], 0, 0, 0);
                acc[mi][ni] = __builtin_amdgcn_mfma_f32_16x16x32_bf16(
                    al[mi], bh[ni], acc[mi][ni], 0, 0, 0);
            }
    }

    // epilogue: r = fl(fl(A+B)-2D'); per-lane top-2 over ni, xor-butterfly
    // over l15, then 2-half merge (first-index ties preserved throughout).
    float env[4];
    #pragma unroll
    for (int ni = 0; ni < 4; ++ni)
        env[ni] = ws[W_ENORM + kc * 128 + candB + ni * 16 + l15];
    #pragma unroll
    for (int mi = 0; mi < 4; ++mi) {
        const f32x4 A4 = *(const f32x4*)&ws[W_A + n0 + tokB + mi * 16 + q * 4];
        #pragma unroll
        for (int r = 0; r < 4; ++r) {
            const float a = A4[r];
            float v1 = 3.4e38f, v2 = 3.4e38f;
            int i1 = 0;
            #pragma unroll
            for (int ni = 0; ni < 4; ++ni) {   // ascending cand id
                const float vv = __fsub_rn(__fadd_rn(a, env[ni]),
                                           __fmul_rn(2.0f, acc[mi][ni][r]));
                const int id = kc * 128 + candB + ni * 16 + l15;
                if (vv < v1) { v2 = v1; v1 = vv; i1 = id; }
                else if (vv < v2) { v2 = vv; }
            }
            #pragma unroll
            for (int s = 1; s < 16; s <<= 1) {
                const float ov1 = __shfl_xor(v1, s);
                const float ov2 = __shfl_xor(v2, s);
                const int   oi1 = __shfl_xor(i1, s);
                const bool owin = (ov1 < v1) || (ov1 == v1 && oi1 < i1);
                const float lose = owin ? v1 : ov1;
                const float wsec = owin ? ov2 : v2;
                v1 = owin ? ov1 : v1;
                i1 = owin ? oi1 : i1;
                v2 = fminf(lose, wsec);
            }
            if (l15 == 0) {
                const int tok = tokB + mi * 16 + q * 4 + r;
                mv1[cg][tok] = v1;
                mv2[cg][tok] = v2;
                mi1[cg][tok] = i1;
            }
        }
    }
    __syncthreads();
    if (t < 128) {   // merge the 2 cand-halves (cg0 ids < cg1 ids on ties)
        const float a1 = mv1[0][t], a2 = mv2[0][t];
        const float b1 = mv1[1][t], b2 = mv2[1][t];
        const int   ia = mi1[0][t], ib = mi1[1][t];
        const bool bwin = (b1 < a1);        // tie -> a (smaller ids) wins
        const float best = bwin ? b1 : a1;
        const int   bi   = bwin ? ib : ia;
        const float sec  = fminf(bwin ? a1 : b1, bwin ? b2 : a2);
        const int slot = kc * 32768 + n0 + t;
        ws[W_V1 + slot] = best;
        ws[W_V2 + slot] = sec;
        ((int*)ws)[W_I1 + slot] = bi;
    }
}

// ---------------------------------------------------------------- epi -------
// Merge 8 chunk top-2s (ascending kc, first-index ties), flag near-ties,
// write idx + one-hot + quantized + loss partials.
__global__ __launch_bounds__(256) void vq_epi(const float* __restrict__ x,
                                              const float* __restrict__ cb,
                                              float* __restrict__ ws,
                                              float* __restrict__ out) {
    const int tile = blockIdx.x;            // 0..511 (64-token tiles)
    const int b    = tile >> 4;
    const int hw0  = (tile & 15) * 64;
    const int n0   = tile * 64;
    const int t    = threadIdx.x;

    __shared__ float qs[32 * 65];           // 8.3KB (bank-conflict pad)
    __shared__ int   idxS[64];
    __shared__ float lred[4];

    if (t < 64) {
        float best = 3.4e38f, sec = 3.4e38f, bv2 = 3.4e38f;
        int bi = 0;
        for (int kc = 0; kc < 8; ++kc) {    // ascending kc => ascending ids
            const int slot = kc * 32768 + n0 + t;
            const float v  = ws[W_V1 + slot];
            const float v2 = ws[W_V2 + slot];
            const int  id  = ((const int*)ws)[W_I1 + slot];
            if (v < best || (v == best && id < bi)) {
                if (best < sec) sec = best;
                best = v; bi = id; bv2 = v2;
            } else if (v < sec) { sec = v; }
        }
        if (bv2 < sec) sec = bv2;
        idxS[t] = bi;
        out[O_IDX + n0 + t] = (float)bi;
        if (sec - best <= FLAG_EPS) {       // near-tie: fp64 re-decision
            const int p = atomicAdd((int*)ws + W_CNT, 1);
            ((int*)ws)[W_FLAGS + p] = n0 + t;
        }
    }
    __syncthreads();

    // one-hot: 64 rows x 1024 cols, one float4 per thread per row
    {
        float* encp = out + O_ENC + (size_t)n0 * K_EMB;
        const int c0 = t * 4;
        for (int row = 0; row < 64; ++row) {
            const int id = idxS[row];
            f32x4 ev;
            ev[0] = (c0     == id) ? 1.0f : 0.0f;
            ev[1] = (c0 + 1 == id) ? 1.0f : 0.0f;
            ev[2] = (c0 + 2 == id) ? 1.0f : 0.0f;
            ev[3] = (c0 + 3 == id) ? 1.0f : 0.0f;
            *(f32x4*)&encp[row * K_EMB + c0] = ev;
        }
    }

    // quantized (= straight-through value) + loss partials
    const float* __restrict__ xbase = x + (size_t)b * CHW + hw0;
    float lacc = 0.0f;
    for (int cc = 0; cc < 256; cc += 32) {
        __syncthreads();
        {   // gather 64 codebook rows' 32-col slice into LDS, transposed
            const int r = t >> 2, part = t & 3;
            const float* crow = cb + (size_t)idxS[r] * D_EMB + cc + part * 8;
            const float4 q0 = *(const float4*)(crow);
            const float4 q1 = *(const float4*)(crow + 4);
            const int cb0 = part * 8;
            qs[(cb0 + 0) * 65 + r] = q0.x; qs[(cb0 + 1) * 65 + r] = q0.y;
            qs[(cb0 + 2) * 65 + r] = q0.z; qs[(cb0 + 3) * 65 + r] = q0.w;
            qs[(cb0 + 4) * 65 + r] = q1.x; qs[(cb0 + 5) * 65 + r] = q1.y;
            qs[(cb0 + 6) * 65 + r] = q1.z; qs[(cb0 + 7) * 65 + r] = q1.w;
        }
        __syncthreads();
        const int tok = t & 63, cgr = t >> 6;
        #pragma unroll
        for (int m = 0; m < 8; ++m) {
            const int cl = cgr * 8 + m;
            const int c  = cc + cl;
            const float qv = qs[cl * 65 + tok];
            const float xv = xbase[(size_t)c * HW_SZ + tok];
            out[O_QUANT + (size_t)b * CHW + (size_t)c * HW_SZ + hw0 + tok] = qv;
            const float d = qv - xv;
            lacc += d * d;
        }
    }
    #pragma unroll
    for (int off = 32; off > 0; off >>= 1) lacc += __shfl_down(lacc, off);
    if ((t & 63) == 0) lred[t >> 6] = lacc;
    __syncthreads();
    if (t == 0)
        atomicAdd(ws + W_LOSS, (lred[0] + lred[1]) + (lred[2] + lred[3]));
}

// --------------------------------------------------------------- refine -----
// One token per block-iteration, ONE candidate per thread (1024 threads):
// fp64 dot rounded to fp32 (ideal np matmul), np op-order fp32 rounding,
// lexicographic (r,k) tree reduce = np first-index argmin. Patches idx,
// one-hot, quantized; writes final loss.
__global__ __launch_bounds__(1024) void vq_refine(const float* __restrict__ x,
                                                  const float* __restrict__ cb,
                                                  const float* __restrict__ ws,
                                                  float* __restrict__ out) {
    if (blockIdx.x == 0 && threadIdx.x == 0)
        out[0] = 1.25f * ws[W_LOSS] / 8388608.0f;
    __shared__ float xs[256];
    __shared__ float rS[1024];
    __shared__ int   kS[1024];
    int cnt = ((const int*)ws)[W_CNT];
    if (cnt > 32768) cnt = 32768;
    const int t = threadIdx.x;
    const float* __restrict__ eN = ws + W_ENORM;
    for (int fi = blockIdx.x; fi < cnt; fi += gridDim.x) {
        const int n  = ((const int*)ws)[W_FLAGS + fi];
        const int b  = n >> 10;
        const int hw = n & 1023;
        __syncthreads();   // protect xs/rS/kS reuse across fi iterations
        if (t < 256) xs[t] = x[(size_t)b * CHW + (size_t)t * HW_SZ + hw];
        __syncthreads();
        const float A = ws[W_A + n];        // same A as vq_main used
        {
            const int k = t;                // one candidate per thread
            const float* row = cb + (size_t)k * D_EMB;
            double d64 = 0.0;
            for (int d = 0; d < 256; ++d)
                d64 = fma((double)row[d], (double)xs[d], d64);
            const float M  = (float)d64;    // ideal np matmul output
            const float T1 = __fadd_rn(A, eN[k]);
            rS[t] = __fsub_rn(T1, __fmul_rn(2.0f, M));
            kS[t] = k;
        }
        __syncthreads();
        for (int off = 512; off > 0; off >>= 1) {
            if (t < off) {
                const float r = rS[t + off]; const int id = kS[t + off];
                if (r < rS[t] || (r == rS[t] && id < kS[t])) {
                    rS[t] = r; kS[t] = id;  // lexicographic (r, k)
                }
            }
            __syncthreads();
        }
        const int newIdx = kS[0];
        if (t == 0) {
            const int oldIdx = (int)out[O_IDX + n];
            out[O_IDX + n] = (float)newIdx;
            out[O_ENC + (size_t)n * K_EMB + oldIdx] = 0.0f;  // same thread:
            out[O_ENC + (size_t)n * K_EMB + newIdx] = 1.0f;  // ordered stores
        }
        if (t < 256)
            out[O_QUANT + (size_t)b * CHW + (size_t)t * HW_SZ + hw] =
                cb[(size_t)newIdx * D_EMB + t];
    }
}

extern "C" void kernel_launch(void* const* d_in, const int* in_sizes, int n_in,
                              void* d_out, int out_size, void* d_ws, size_t ws_size,
                              hipStream_t stream) {
    (void)in_sizes; (void)n_in; (void)out_size; (void)ws_size;
    const float* x  = (const float*)d_in[0];
    const float* cb = (const float*)d_in[1];
    float* out = (float*)d_out;
    float* ws  = (float*)d_ws;
    hipLaunchKernelGGL(vq_prep,   dim3(192),  dim3(256),  0, stream, cb, x, ws);
    hipLaunchKernelGGL(vq_main,   dim3(2048), dim3(256),  0, stream, x, ws);
    hipLaunchKernelGGL(vq_epi,    dim3(512),  dim3(256),  0, stream, x, cb, ws, out);
    hipLaunchKernelGGL(vq_refine, dim3(1024), dim3(1024), 0, stream, x, cb, ws, out);
}